// Round 3
// baseline (582.349 us; speedup 1.0000x reference)
//
#include <hip/hip_runtime.h>
#include <math.h>

constexpr int Lq = 8, Cq = 16, Hq = 240, Wq = 480, Rq = 8, MIDq = 8, SEM = 4;
constexpr int HWq = Hq * Wq;

__device__ __forceinline__ float sigmoidf_(float v) { return 1.0f / (1.0f + expf(-v)); }

// conv1: x (L,16,H,W) -> silu -> f1 (L,8,H,W), 3x3 SAME zero-pad.
__global__ void k_conv1(const float* __restrict__ x, const float* __restrict__ w1,
                        const float* __restrict__ b1, float* __restrict__ f1) {
    int b = blockIdx.x;
    int l = b & 7, y = b >> 3;
    int t = threadIdx.x;
    if (t >= Wq / 4) return;
    int xi = t * 4;
    float acc[MIDq][4];
#pragma unroll
    for (int m = 0; m < MIDq; m++) {
        float bv = b1[m];
#pragma unroll
        for (int o = 0; o < 4; o++) acc[m][o] = bv;
    }
#pragma unroll 1
    for (int ic = 0; ic < Cq; ic++) {
        const float* xin = x + (size_t)(l * Cq + ic) * HWq;
        const float* wrow = w1 + ic * 9;
#pragma unroll
        for (int r = 0; r < 3; r++) {
            int yy = y + r - 1;
            if (yy < 0 || yy >= Hq) continue;
            const float* rp = xin + yy * Wq;
            float4 mid = *(const float4*)(rp + xi);
            float lft = (xi > 0) ? rp[xi - 1] : 0.f;
            float rgt = (xi + 4 < Wq) ? rp[xi + 4] : 0.f;
            float in6[6] = {lft, mid.x, mid.y, mid.z, mid.w, rgt};
#pragma unroll
            for (int m = 0; m < MIDq; m++) {
                const float* wp = wrow + m * (Cq * 9) + r * 3;
                float w0 = wp[0], w1v = wp[1], w2 = wp[2];
#pragma unroll
                for (int o = 0; o < 4; o++)
                    acc[m][o] = fmaf(w0, in6[o],
                                fmaf(w1v, in6[o + 1],
                                fmaf(w2, in6[o + 2], acc[m][o])));
            }
        }
    }
    size_t rowoff = (size_t)y * Wq + xi;
#pragma unroll
    for (int m = 0; m < MIDq; m++) {
        float4 v;
        float a0 = acc[m][0], a1 = acc[m][1], a2 = acc[m][2], a3 = acc[m][3];
        v.x = a0 * sigmoidf_(a0);
        v.y = a1 * sigmoidf_(a1);
        v.z = a2 * sigmoidf_(a2);
        v.w = a3 * sigmoidf_(a3);
        *(float4*)(f1 + (size_t)(l * MIDq + m) * HWq + rowoff) = v;
    }
}

// conv2: f1 (L,8,H,W) -> f (L,2,H,W), 3x3 SAME zero-pad.
__global__ void k_conv2(const float* __restrict__ f1, const float* __restrict__ w2,
                        const float* __restrict__ b2, float* __restrict__ f) {
    int b = blockIdx.x;
    int l = b & 7, y = b >> 3;
    int t = threadIdx.x;
    if (t >= Wq / 4) return;
    int xi = t * 4;
    float acc[2][4];
#pragma unroll
    for (int m = 0; m < 2; m++) {
        float bv = b2[m];
#pragma unroll
        for (int o = 0; o < 4; o++) acc[m][o] = bv;
    }
#pragma unroll 1
    for (int ic = 0; ic < MIDq; ic++) {
        const float* fin = f1 + (size_t)(l * MIDq + ic) * HWq;
        const float* wrow = w2 + ic * 9;
#pragma unroll
        for (int r = 0; r < 3; r++) {
            int yy = y + r - 1;
            if (yy < 0 || yy >= Hq) continue;
            const float* rp = fin + yy * Wq;
            float4 mid = *(const float4*)(rp + xi);
            float lft = (xi > 0) ? rp[xi - 1] : 0.f;
            float rgt = (xi + 4 < Wq) ? rp[xi + 4] : 0.f;
            float in6[6] = {lft, mid.x, mid.y, mid.z, mid.w, rgt};
#pragma unroll
            for (int m = 0; m < 2; m++) {
                const float* wp = wrow + m * (MIDq * 9) + r * 3;
                float w0 = wp[0], w1v = wp[1], w2v = wp[2];
#pragma unroll
                for (int o = 0; o < 4; o++)
                    acc[m][o] = fmaf(w0, in6[o],
                                fmaf(w1v, in6[o + 1],
                                fmaf(w2v, in6[o + 2], acc[m][o])));
            }
        }
    }
    size_t rowoff = (size_t)y * Wq + xi;
#pragma unroll
    for (int m = 0; m < 2; m++) {
        float4 v = {acc[m][0], acc[m][1], acc[m][2], acc[m][3]};
        *(float4*)(f + (size_t)(l * 2 + m) * HWq + rowoff) = v;
    }
}

// sobel (wrap-x, edge-y) + metric + tanh -> flow (L,2,H,W)
__global__ void k_flow(const float* __restrict__ f, float* __restrict__ flow) {
    int idx = blockIdx.x * blockDim.x + threadIdx.x;
    if (idx >= Lq * HWq) return;
    int l = idx / HWq, rem = idx % HWq, y = rem / Wq, x = rem % Wq;
    const float* phi = f + (size_t)(l * 2 + 0) * HWq;
    const float* psi = f + (size_t)(l * 2 + 1) * HWq;
    float ph[3][3], ps[3][3];
#pragma unroll
    for (int i = 0; i < 3; i++) {
        int yy = y + i - 1;
        yy = yy < 0 ? 0 : (yy >= Hq ? Hq - 1 : yy);
#pragma unroll
        for (int j = 0; j < 3; j++) {
            int xx = x + j - 1;
            xx = (xx + Wq) % Wq;
            ph[i][j] = phi[yy * Wq + xx];
            ps[i][j] = psi[yy * Wq + xx];
        }
    }
    float gxp = (ph[0][2] - ph[0][0]) + 2.f * (ph[1][2] - ph[1][0]) + (ph[2][2] - ph[2][0]);
    float gyp = (ph[2][0] + 2.f * ph[2][1] + ph[2][2]) - (ph[0][0] + 2.f * ph[0][1] + ph[0][2]);
    float gxs = (ps[0][2] - ps[0][0]) + 2.f * (ps[1][2] - ps[1][0]) + (ps[2][2] - ps[2][0]);
    float gys = (ps[2][0] + 2.f * ps[2][1] + ps[2][2]) - (ps[0][0] + 2.f * ps[0][1] + ps[0][2]);
    float latf = (float)(-M_PI * 0.5 + (double)y * (M_PI / (double)(Hq - 1)));
    float metric = (float)(1.0 / (cos((double)latf) + 1e-6));
    float u = gxp * metric - gys;
    float v = gyp + gxs * metric;
    flow[(size_t)(l * 2 + 0) * HWq + rem] = tanhf(u);
    flow[(size_t)(l * 2 + 1) * HWq + rem] = tanhf(v);
}

// warp (bilinear, border clamp) + add x_t + mean over R + row sums.
// grid: 960 blocks, bid = g*16 + c  ->  bid%8 == c%8 : channel pinned to XCD,
// y-groups ascend in time on that XCD -> h-row halo reuse hits L2.
// 4 waves/block, one wave per row, shfl-only reduction (no barriers).
__global__ void k_warp(const float* __restrict__ hin, float* __restrict__ hout,
                       const float* __restrict__ flow_l, const float* __restrict__ xl,
                       const float* __restrict__ listT, int l,
                       float* __restrict__ xf, float* __restrict__ rowsum) {
    int bid = blockIdx.x;
    int c = bid & 15;
    int g = bid >> 4;
    int wave = threadIdx.x >> 6;
    int lane = threadIdx.x & 63;
    int y = g * 4 + wave;
    float dt = listT[l];
    float gyn = y * (2.0f / (Hq - 1)) - 1.0f;
    const float4* h4 = (const float4*)hin;
    float4* o4 = (float4*)hout;
    const float* flu = flow_l + y * Wq;
    const float* flv = flow_l + HWq + y * Wq;
    const float* xrow = xl + (size_t)c * HWq + y * Wq;
    float* xfrow = xf + (size_t)(c * Hq + y) * Wq;
    float partial = 0.f;
#pragma unroll 2
    for (int x = lane; x < Wq; x += 64) {
        float u = flu[x];
        float v = flv[x];
        float gxn = x * (2.0f / (Wq - 1)) - 1.0f;
        float gx = gxn - u * dt;
        float gy = gyn - v * dt;
        float xp = (gx + 1.0f) * (Wq * 0.5f) - 0.5f;
        float yp = (gy + 1.0f) * (Hq * 0.5f) - 0.5f;
        xp = fminf(fmaxf(xp, 0.0f), (float)(Wq - 1));
        yp = fminf(fmaxf(yp, 0.0f), (float)(Hq - 1));
        float x0f = floorf(xp), y0f = floorf(yp);
        float wx = xp - x0f, wy = yp - y0f;
        int x0 = (int)x0f, y0 = (int)y0f;
        int x1 = min(x0 + 1, Wq - 1), y1 = min(y0 + 1, Hq - 1);
        int p00 = ((c * Hq + y0) * Wq + x0) * 2, p01 = ((c * Hq + y0) * Wq + x1) * 2;
        int p10 = ((c * Hq + y1) * Wq + x0) * 2, p11 = ((c * Hq + y1) * Wq + x1) * 2;
        float w00 = (1.f - wx) * (1.f - wy), w01 = wx * (1.f - wy);
        float w10 = (1.f - wx) * wy, w11 = wx * wy;
        float4 a0 = h4[p00], b0 = h4[p01], c0 = h4[p10], d0 = h4[p11];
        float4 a1 = h4[p00 + 1], b1 = h4[p01 + 1], c1 = h4[p10 + 1], d1 = h4[p11 + 1];
        float4 r0, r1;
        r0.x = w00 * a0.x + w01 * b0.x + w10 * c0.x + w11 * d0.x;
        r0.y = w00 * a0.y + w01 * b0.y + w10 * c0.y + w11 * d0.y;
        r0.z = w00 * a0.z + w01 * b0.z + w10 * c0.z + w11 * d0.z;
        r0.w = w00 * a0.w + w01 * b0.w + w10 * c0.w + w11 * d0.w;
        r1.x = w00 * a1.x + w01 * b1.x + w10 * c1.x + w11 * d1.x;
        r1.y = w00 * a1.y + w01 * b1.y + w10 * c1.y + w11 * d1.y;
        r1.z = w00 * a1.z + w01 * b1.z + w10 * c1.z + w11 * d1.z;
        r1.w = w00 * a1.w + w01 * b1.w + w10 * c1.w + w11 * d1.w;
        float ssum = r0.x + r0.y + r0.z + r0.w + r1.x + r1.y + r1.z + r1.w;
        float xt = xrow[x];
        r0.x += xt; r0.y += xt; r0.z += xt; r0.w += xt;
        r1.x += xt; r1.y += xt; r1.z += xt; r1.w += xt;
        int po = ((c * Hq + y) * Wq + x) * 2;
        o4[po] = r0;
        o4[po + 1] = r1;
        float meanv = ssum * 0.125f + xt;
        xfrow[x] = meanv;
        partial += meanv;
    }
#pragma unroll
    for (int off = 32; off > 0; off >>= 1) partial += __shfl_down(partial, off, 64);
    if (lane == 0) rowsum[c * Hq + y] = partial;
}

// SE gate (recomputed per block from rowsums) + apply: out = xf * gate
__global__ void k_apply(const float* __restrict__ xf, const float* __restrict__ rowsum,
                        const float* __restrict__ sw1, const float* __restrict__ sb1,
                        const float* __restrict__ sw2, const float* __restrict__ sb2,
                        float* __restrict__ out_l) {
    int c = blockIdx.x / Hq, y = blockIdx.x % Hq;
    float ym[Cq];
#pragma unroll
    for (int i = 0; i < Cq; i++) ym[i] = rowsum[i * Hq + y] * (1.0f / Wq);
    float z[SEM];
#pragma unroll
    for (int m = 0; m < SEM; m++) {
        float a = sb1[m];
#pragma unroll
        for (int i = 0; i < Cq; i++) a = fmaf(sw1[m * Cq + i], ym[i], a);
        z[m] = a * sigmoidf_(a);
    }
    float a = sb2[c];
#pragma unroll
    for (int m = 0; m < SEM; m++) a = fmaf(sw2[c * SEM + m], z[m], a);
    float gv = sigmoidf_(a);
    const float4* s4 = (const float4*)(xf + (size_t)(c * Hq + y) * Wq);
    float4* d4 = (float4*)(out_l + (size_t)(c * Hq + y) * Wq);
    for (int i = threadIdx.x; i < Wq / 4; i += blockDim.x) {
        float4 v = s4[i];
        v.x *= gv; v.y *= gv; v.z *= gv; v.w *= gv;
        d4[i] = v;
    }
}

extern "C" void kernel_launch(void* const* d_in, const int* in_sizes, int n_in,
                              void* d_out, int out_size, void* d_ws, size_t ws_size,
                              hipStream_t stream) {
    const float* x = (const float*)d_in[0];
    const float* h0 = (const float*)d_in[1];
    const float* listT = (const float*)d_in[2];
    const float* hw1 = (const float*)d_in[3];
    const float* hb1 = (const float*)d_in[4];
    const float* hw2 = (const float*)d_in[5];
    const float* hb2 = (const float*)d_in[6];
    const float* sw1 = (const float*)d_in[7];
    const float* sb1 = (const float*)d_in[8];
    const float* sw2 = (const float*)d_in[9];
    const float* sb2 = (const float*)d_in[10];
    float* out = (float*)d_out;
    float* ws = (float*)d_ws;

    size_t off = 0;
    float* flow = ws + off; off += (size_t)Lq * 2 * HWq;
    float* f    = ws + off; off += (size_t)Lq * 2 * HWq;
    float* f1   = ws + off; off += (size_t)Lq * MIDq * HWq;
    float* hA   = ws + off; off += (size_t)Cq * HWq * Rq;
    float* hB   = ws + off; off += (size_t)Cq * HWq * Rq;
    float* xf   = ws + off; off += (size_t)Cq * HWq;
    float* rows = ws + off; off += (size_t)Cq * Hq;

    k_conv1<<<Lq * Hq, 128, 0, stream>>>(x, hw1, hb1, f1);
    k_conv2<<<Lq * Hq, 128, 0, stream>>>(f1, hw2, hb2, f);
    k_flow<<<(Lq * HWq + 255) / 256, 256, 0, stream>>>(f, flow);

    const float* hin = h0;
    float* bufs[2] = {hA, hB};
    for (int l = 0; l < Lq; l++) {
        float* hout = bufs[l & 1];
        k_warp<<<Cq * (Hq / 4), 256, 0, stream>>>(hin, hout, flow + (size_t)l * 2 * HWq,
                                                  x + (size_t)l * Cq * HWq, listT, l, xf, rows);
        k_apply<<<Cq * Hq, 128, 0, stream>>>(xf, rows, sw1, sb1, sw2, sb2,
                                             out + (size_t)l * Cq * HWq);
        hin = hout;
    }
}

// Round 4
// 489.582 us; speedup vs baseline: 1.1895x; 1.1895x over previous
//
#include <hip/hip_runtime.h>
#include <math.h>

constexpr int Lq = 8, Cq = 16, Hq = 240, Wq = 480, Rq = 8, MIDq = 8, SEM = 4;
constexpr int HWq = Hq * Wq;

__device__ __forceinline__ float sigmoidf_(float v) { return 1.0f / (1.0f + expf(-v)); }

// conv1: x (L,16,H,W) -> silu -> f1 (L,8,H,W), 3x3 SAME zero-pad.
__global__ void k_conv1(const float* __restrict__ x, const float* __restrict__ w1,
                        const float* __restrict__ b1, float* __restrict__ f1) {
    int b = blockIdx.x;
    int l = b & 7, y = b >> 3;
    int t = threadIdx.x;
    if (t >= Wq / 4) return;
    int xi = t * 4;
    float acc[MIDq][4];
#pragma unroll
    for (int m = 0; m < MIDq; m++) {
        float bv = b1[m];
#pragma unroll
        for (int o = 0; o < 4; o++) acc[m][o] = bv;
    }
#pragma unroll 1
    for (int ic = 0; ic < Cq; ic++) {
        const float* xin = x + (size_t)(l * Cq + ic) * HWq;
        const float* wrow = w1 + ic * 9;
#pragma unroll
        for (int r = 0; r < 3; r++) {
            int yy = y + r - 1;
            if (yy < 0 || yy >= Hq) continue;
            const float* rp = xin + yy * Wq;
            float4 mid = *(const float4*)(rp + xi);
            float lft = (xi > 0) ? rp[xi - 1] : 0.f;
            float rgt = (xi + 4 < Wq) ? rp[xi + 4] : 0.f;
            float in6[6] = {lft, mid.x, mid.y, mid.z, mid.w, rgt};
#pragma unroll
            for (int m = 0; m < MIDq; m++) {
                const float* wp = wrow + m * (Cq * 9) + r * 3;
                float w0 = wp[0], w1v = wp[1], w2 = wp[2];
#pragma unroll
                for (int o = 0; o < 4; o++)
                    acc[m][o] = fmaf(w0, in6[o],
                                fmaf(w1v, in6[o + 1],
                                fmaf(w2, in6[o + 2], acc[m][o])));
            }
        }
    }
    size_t rowoff = (size_t)y * Wq + xi;
#pragma unroll
    for (int m = 0; m < MIDq; m++) {
        float4 v;
        float a0 = acc[m][0], a1 = acc[m][1], a2 = acc[m][2], a3 = acc[m][3];
        v.x = a0 * sigmoidf_(a0);
        v.y = a1 * sigmoidf_(a1);
        v.z = a2 * sigmoidf_(a2);
        v.w = a3 * sigmoidf_(a3);
        *(float4*)(f1 + (size_t)(l * MIDq + m) * HWq + rowoff) = v;
    }
}

// conv2: f1 (L,8,H,W) -> f (L,2,H,W), 3x3 SAME zero-pad.
__global__ void k_conv2(const float* __restrict__ f1, const float* __restrict__ w2,
                        const float* __restrict__ b2, float* __restrict__ f) {
    int b = blockIdx.x;
    int l = b & 7, y = b >> 3;
    int t = threadIdx.x;
    if (t >= Wq / 4) return;
    int xi = t * 4;
    float acc[2][4];
#pragma unroll
    for (int m = 0; m < 2; m++) {
        float bv = b2[m];
#pragma unroll
        for (int o = 0; o < 4; o++) acc[m][o] = bv;
    }
#pragma unroll 1
    for (int ic = 0; ic < MIDq; ic++) {
        const float* fin = f1 + (size_t)(l * MIDq + ic) * HWq;
        const float* wrow = w2 + ic * 9;
#pragma unroll
        for (int r = 0; r < 3; r++) {
            int yy = y + r - 1;
            if (yy < 0 || yy >= Hq) continue;
            const float* rp = fin + yy * Wq;
            float4 mid = *(const float4*)(rp + xi);
            float lft = (xi > 0) ? rp[xi - 1] : 0.f;
            float rgt = (xi + 4 < Wq) ? rp[xi + 4] : 0.f;
            float in6[6] = {lft, mid.x, mid.y, mid.z, mid.w, rgt};
#pragma unroll
            for (int m = 0; m < 2; m++) {
                const float* wp = wrow + m * (MIDq * 9) + r * 3;
                float w0 = wp[0], w1v = wp[1], w2v = wp[2];
#pragma unroll
                for (int o = 0; o < 4; o++)
                    acc[m][o] = fmaf(w0, in6[o],
                                fmaf(w1v, in6[o + 1],
                                fmaf(w2v, in6[o + 2], acc[m][o])));
            }
        }
    }
    size_t rowoff = (size_t)y * Wq + xi;
#pragma unroll
    for (int m = 0; m < 2; m++) {
        float4 v = {acc[m][0], acc[m][1], acc[m][2], acc[m][3]};
        *(float4*)(f + (size_t)(l * 2 + m) * HWq + rowoff) = v;
    }
}

// sobel (wrap-x, edge-y) + metric + tanh -> flow (L,2,H,W)
__global__ void k_flow(const float* __restrict__ f, float* __restrict__ flow) {
    int idx = blockIdx.x * blockDim.x + threadIdx.x;
    if (idx >= Lq * HWq) return;
    int l = idx / HWq, rem = idx % HWq, y = rem / Wq, x = rem % Wq;
    const float* phi = f + (size_t)(l * 2 + 0) * HWq;
    const float* psi = f + (size_t)(l * 2 + 1) * HWq;
    float ph[3][3], ps[3][3];
#pragma unroll
    for (int i = 0; i < 3; i++) {
        int yy = y + i - 1;
        yy = yy < 0 ? 0 : (yy >= Hq ? Hq - 1 : yy);
#pragma unroll
        for (int j = 0; j < 3; j++) {
            int xx = x + j - 1;
            xx = (xx + Wq) % Wq;
            ph[i][j] = phi[yy * Wq + xx];
            ps[i][j] = psi[yy * Wq + xx];
        }
    }
    float gxp = (ph[0][2] - ph[0][0]) + 2.f * (ph[1][2] - ph[1][0]) + (ph[2][2] - ph[2][0]);
    float gyp = (ph[2][0] + 2.f * ph[2][1] + ph[2][2]) - (ph[0][0] + 2.f * ph[0][1] + ph[0][2]);
    float gxs = (ps[0][2] - ps[0][0]) + 2.f * (ps[1][2] - ps[1][0]) + (ps[2][2] - ps[2][0]);
    float gys = (ps[2][0] + 2.f * ps[2][1] + ps[2][2]) - (ps[0][0] + 2.f * ps[0][1] + ps[0][2]);
    float latf = (float)(-M_PI * 0.5 + (double)y * (M_PI / (double)(Hq - 1)));
    float metric = (float)(1.0 / (cos((double)latf) + 1e-6));
    float u = gxp * metric - gys;
    float v = gyp + gxs * metric;
    flow[(size_t)(l * 2 + 0) * HWq + rem] = tanhf(u);
    flow[(size_t)(l * 2 + 1) * HWq + rem] = tanhf(v);
}

// warp (bilinear, border clamp) + add x_t + mean over R + row sums.
// grid: 3840 blocks (one per (c,y) row), 256 thr. Swizzle keeps channel
// pinned to one XCD (bid&7) with ascending y -> h-row halo reuse in L2,
// while 15360 waves saturate the machine (R3 lesson: 3840 waves was
// latency-starved at 33% occupancy).
__global__ void k_warp(const float* __restrict__ hin, float* __restrict__ hout,
                       const float* __restrict__ flow_l, const float* __restrict__ xl,
                       const float* __restrict__ listT, int l,
                       float* __restrict__ xf, float* __restrict__ rowsum) {
    int bid = blockIdx.x;
    int xcd = bid & 7;
    int local = bid >> 3;            // 0..479
    int c = xcd + 8 * (local / Hq);  // 0..15, c%8 == xcd
    int y = local % Hq;
    int tid = threadIdx.x;
    int wave = tid >> 6, lane = tid & 63;
    float dt = listT[l];
    float gyn = y * (2.0f / (Hq - 1)) - 1.0f;
    const float4* h4 = (const float4*)hin;
    float4* o4 = (float4*)hout;
    const float* flu = flow_l + y * Wq;
    const float* flv = flow_l + HWq + y * Wq;
    const float* xrow = xl + (size_t)c * HWq + y * Wq;
    float* xfrow = xf + (size_t)(c * Hq + y) * Wq;
    float partial = 0.f;
#pragma unroll 2
    for (int x = tid; x < Wq; x += 256) {
        float u = flu[x];
        float v = flv[x];
        float gxn = x * (2.0f / (Wq - 1)) - 1.0f;
        float gx = gxn - u * dt;
        float gy = gyn - v * dt;
        float xp = (gx + 1.0f) * (Wq * 0.5f) - 0.5f;
        float yp = (gy + 1.0f) * (Hq * 0.5f) - 0.5f;
        xp = fminf(fmaxf(xp, 0.0f), (float)(Wq - 1));
        yp = fminf(fmaxf(yp, 0.0f), (float)(Hq - 1));
        float x0f = floorf(xp), y0f = floorf(yp);
        float wx = xp - x0f, wy = yp - y0f;
        int x0 = (int)x0f, y0 = (int)y0f;
        int x1 = min(x0 + 1, Wq - 1), y1 = min(y0 + 1, Hq - 1);
        int p00 = ((c * Hq + y0) * Wq + x0) * 2, p01 = ((c * Hq + y0) * Wq + x1) * 2;
        int p10 = ((c * Hq + y1) * Wq + x0) * 2, p11 = ((c * Hq + y1) * Wq + x1) * 2;
        float w00 = (1.f - wx) * (1.f - wy), w01 = wx * (1.f - wy);
        float w10 = (1.f - wx) * wy, w11 = wx * wy;
        float4 a0 = h4[p00], b0 = h4[p01], c0 = h4[p10], d0 = h4[p11];
        float4 a1 = h4[p00 + 1], b1 = h4[p01 + 1], c1 = h4[p10 + 1], d1 = h4[p11 + 1];
        float4 r0, r1;
        r0.x = w00 * a0.x + w01 * b0.x + w10 * c0.x + w11 * d0.x;
        r0.y = w00 * a0.y + w01 * b0.y + w10 * c0.y + w11 * d0.y;
        r0.z = w00 * a0.z + w01 * b0.z + w10 * c0.z + w11 * d0.z;
        r0.w = w00 * a0.w + w01 * b0.w + w10 * c0.w + w11 * d0.w;
        r1.x = w00 * a1.x + w01 * b1.x + w10 * c1.x + w11 * d1.x;
        r1.y = w00 * a1.y + w01 * b1.y + w10 * c1.y + w11 * d1.y;
        r1.z = w00 * a1.z + w01 * b1.z + w10 * c1.z + w11 * d1.z;
        r1.w = w00 * a1.w + w01 * b1.w + w10 * c1.w + w11 * d1.w;
        float ssum = r0.x + r0.y + r0.z + r0.w + r1.x + r1.y + r1.z + r1.w;
        float xt = xrow[x];
        r0.x += xt; r0.y += xt; r0.z += xt; r0.w += xt;
        r1.x += xt; r1.y += xt; r1.z += xt; r1.w += xt;
        int po = ((c * Hq + y) * Wq + x) * 2;
        o4[po] = r0;
        o4[po + 1] = r1;
        float meanv = ssum * 0.125f + xt;
        xfrow[x] = meanv;
        partial += meanv;
    }
#pragma unroll
    for (int off = 32; off > 0; off >>= 1) partial += __shfl_down(partial, off, 64);
    __shared__ float sred[4];
    if (lane == 0) sred[wave] = partial;
    __syncthreads();
    if (tid == 0) rowsum[c * Hq + y] = sred[0] + sred[1] + sred[2] + sred[3];
}

// SE gate (recomputed per block from rowsums) + apply: out = xf * gate
__global__ void k_apply(const float* __restrict__ xf, const float* __restrict__ rowsum,
                        const float* __restrict__ sw1, const float* __restrict__ sb1,
                        const float* __restrict__ sw2, const float* __restrict__ sb2,
                        float* __restrict__ out_l) {
    int c = blockIdx.x / Hq, y = blockIdx.x % Hq;
    float ym[Cq];
#pragma unroll
    for (int i = 0; i < Cq; i++) ym[i] = rowsum[i * Hq + y] * (1.0f / Wq);
    float z[SEM];
#pragma unroll
    for (int m = 0; m < SEM; m++) {
        float a = sb1[m];
#pragma unroll
        for (int i = 0; i < Cq; i++) a = fmaf(sw1[m * Cq + i], ym[i], a);
        z[m] = a * sigmoidf_(a);
    }
    float a = sb2[c];
#pragma unroll
    for (int m = 0; m < SEM; m++) a = fmaf(sw2[c * SEM + m], z[m], a);
    float gv = sigmoidf_(a);
    const float4* s4 = (const float4*)(xf + (size_t)(c * Hq + y) * Wq);
    float4* d4 = (float4*)(out_l + (size_t)(c * Hq + y) * Wq);
    for (int i = threadIdx.x; i < Wq / 4; i += blockDim.x) {
        float4 v = s4[i];
        v.x *= gv; v.y *= gv; v.z *= gv; v.w *= gv;
        d4[i] = v;
    }
}

extern "C" void kernel_launch(void* const* d_in, const int* in_sizes, int n_in,
                              void* d_out, int out_size, void* d_ws, size_t ws_size,
                              hipStream_t stream) {
    const float* x = (const float*)d_in[0];
    const float* h0 = (const float*)d_in[1];
    const float* listT = (const float*)d_in[2];
    const float* hw1 = (const float*)d_in[3];
    const float* hb1 = (const float*)d_in[4];
    const float* hw2 = (const float*)d_in[5];
    const float* hb2 = (const float*)d_in[6];
    const float* sw1 = (const float*)d_in[7];
    const float* sb1 = (const float*)d_in[8];
    const float* sw2 = (const float*)d_in[9];
    const float* sb2 = (const float*)d_in[10];
    float* out = (float*)d_out;
    float* ws = (float*)d_ws;

    size_t off = 0;
    float* flow = ws + off; off += (size_t)Lq * 2 * HWq;
    float* f    = ws + off; off += (size_t)Lq * 2 * HWq;
    float* f1   = ws + off; off += (size_t)Lq * MIDq * HWq;
    float* hA   = ws + off; off += (size_t)Cq * HWq * Rq;
    float* hB   = ws + off; off += (size_t)Cq * HWq * Rq;
    float* xf   = ws + off; off += (size_t)Cq * HWq;
    float* rows = ws + off; off += (size_t)Cq * Hq;

    k_conv1<<<Lq * Hq, 128, 0, stream>>>(x, hw1, hb1, f1);
    k_conv2<<<Lq * Hq, 128, 0, stream>>>(f1, hw2, hb2, f);
    k_flow<<<(Lq * HWq + 255) / 256, 256, 0, stream>>>(f, flow);

    const float* hin = h0;
    float* bufs[2] = {hA, hB};
    for (int l = 0; l < Lq; l++) {
        float* hout = bufs[l & 1];
        k_warp<<<Cq * Hq, 256, 0, stream>>>(hin, hout, flow + (size_t)l * 2 * HWq,
                                            x + (size_t)l * Cq * HWq, listT, l, xf, rows);
        k_apply<<<Cq * Hq, 128, 0, stream>>>(xf, rows, sw1, sb1, sw2, sb2,
                                             out + (size_t)l * Cq * HWq);
        hin = hout;
    }
}

// Round 5
// 347.191 us; speedup vs baseline: 1.6773x; 1.4101x over previous
//
#include <hip/hip_runtime.h>
#include <hip/hip_fp16.h>
#include <math.h>

constexpr int Lq = 8, Cq = 16, Hq = 240, Wq = 480, Rq = 8, MIDq = 8, SEM = 4;
constexpr int HWq = Hq * Wq;

__device__ __forceinline__ float sigmoidf_(float v) { return 1.0f / (1.0f + expf(-v)); }

struct alignas(16) h8 { __half v[8]; };

// conv1: x (L,16,H,W) -> silu -> f1 (L,8,H,W), 3x3 SAME zero-pad.
__global__ void k_conv1(const float* __restrict__ x, const float* __restrict__ w1,
                        const float* __restrict__ b1, float* __restrict__ f1) {
    int b = blockIdx.x;
    int l = b & 7, y = b >> 3;
    int t = threadIdx.x;
    if (t >= Wq / 4) return;
    int xi = t * 4;
    float acc[MIDq][4];
#pragma unroll
    for (int m = 0; m < MIDq; m++) {
        float bv = b1[m];
#pragma unroll
        for (int o = 0; o < 4; o++) acc[m][o] = bv;
    }
#pragma unroll 1
    for (int ic = 0; ic < Cq; ic++) {
        const float* xin = x + (size_t)(l * Cq + ic) * HWq;
        const float* wrow = w1 + ic * 9;
#pragma unroll
        for (int r = 0; r < 3; r++) {
            int yy = y + r - 1;
            if (yy < 0 || yy >= Hq) continue;
            const float* rp = xin + yy * Wq;
            float4 mid = *(const float4*)(rp + xi);
            float lft = (xi > 0) ? rp[xi - 1] : 0.f;
            float rgt = (xi + 4 < Wq) ? rp[xi + 4] : 0.f;
            float in6[6] = {lft, mid.x, mid.y, mid.z, mid.w, rgt};
#pragma unroll
            for (int m = 0; m < MIDq; m++) {
                const float* wp = wrow + m * (Cq * 9) + r * 3;
                float w0 = wp[0], w1v = wp[1], w2 = wp[2];
#pragma unroll
                for (int o = 0; o < 4; o++)
                    acc[m][o] = fmaf(w0, in6[o],
                                fmaf(w1v, in6[o + 1],
                                fmaf(w2, in6[o + 2], acc[m][o])));
            }
        }
    }
    size_t rowoff = (size_t)y * Wq + xi;
#pragma unroll
    for (int m = 0; m < MIDq; m++) {
        float4 v;
        float a0 = acc[m][0], a1 = acc[m][1], a2 = acc[m][2], a3 = acc[m][3];
        v.x = a0 * sigmoidf_(a0);
        v.y = a1 * sigmoidf_(a1);
        v.z = a2 * sigmoidf_(a2);
        v.w = a3 * sigmoidf_(a3);
        *(float4*)(f1 + (size_t)(l * MIDq + m) * HWq + rowoff) = v;
    }
}

// conv2: f1 (L,8,H,W) -> f (L,2,H,W), 3x3 SAME zero-pad.
__global__ void k_conv2(const float* __restrict__ f1, const float* __restrict__ w2,
                        const float* __restrict__ b2, float* __restrict__ f) {
    int b = blockIdx.x;
    int l = b & 7, y = b >> 3;
    int t = threadIdx.x;
    if (t >= Wq / 4) return;
    int xi = t * 4;
    float acc[2][4];
#pragma unroll
    for (int m = 0; m < 2; m++) {
        float bv = b2[m];
#pragma unroll
        for (int o = 0; o < 4; o++) acc[m][o] = bv;
    }
#pragma unroll 1
    for (int ic = 0; ic < MIDq; ic++) {
        const float* fin = f1 + (size_t)(l * MIDq + ic) * HWq;
        const float* wrow = w2 + ic * 9;
#pragma unroll
        for (int r = 0; r < 3; r++) {
            int yy = y + r - 1;
            if (yy < 0 || yy >= Hq) continue;
            const float* rp = fin + yy * Wq;
            float4 mid = *(const float4*)(rp + xi);
            float lft = (xi > 0) ? rp[xi - 1] : 0.f;
            float rgt = (xi + 4 < Wq) ? rp[xi + 4] : 0.f;
            float in6[6] = {lft, mid.x, mid.y, mid.z, mid.w, rgt};
#pragma unroll
            for (int m = 0; m < 2; m++) {
                const float* wp = wrow + m * (MIDq * 9) + r * 3;
                float w0 = wp[0], w1v = wp[1], w2v = wp[2];
#pragma unroll
                for (int o = 0; o < 4; o++)
                    acc[m][o] = fmaf(w0, in6[o],
                                fmaf(w1v, in6[o + 1],
                                fmaf(w2v, in6[o + 2], acc[m][o])));
            }
        }
    }
    size_t rowoff = (size_t)y * Wq + xi;
#pragma unroll
    for (int m = 0; m < 2; m++) {
        float4 v = {acc[m][0], acc[m][1], acc[m][2], acc[m][3]};
        *(float4*)(f + (size_t)(l * 2 + m) * HWq + rowoff) = v;
    }
}

// sobel (wrap-x, edge-y) + metric + tanh -> flow (L,2,H,W)
__global__ void k_flow(const float* __restrict__ f, float* __restrict__ flow) {
    int idx = blockIdx.x * blockDim.x + threadIdx.x;
    if (idx >= Lq * HWq) return;
    int l = idx / HWq, rem = idx % HWq, y = rem / Wq, x = rem % Wq;
    const float* phi = f + (size_t)(l * 2 + 0) * HWq;
    const float* psi = f + (size_t)(l * 2 + 1) * HWq;
    float ph[3][3], ps[3][3];
#pragma unroll
    for (int i = 0; i < 3; i++) {
        int yy = y + i - 1;
        yy = yy < 0 ? 0 : (yy >= Hq ? Hq - 1 : yy);
#pragma unroll
        for (int j = 0; j < 3; j++) {
            int xx = x + j - 1;
            xx = (xx + Wq) % Wq;
            ph[i][j] = phi[yy * Wq + xx];
            ps[i][j] = psi[yy * Wq + xx];
        }
    }
    float gxp = (ph[0][2] - ph[0][0]) + 2.f * (ph[1][2] - ph[1][0]) + (ph[2][2] - ph[2][0]);
    float gyp = (ph[2][0] + 2.f * ph[2][1] + ph[2][2]) - (ph[0][0] + 2.f * ph[0][1] + ph[0][2]);
    float gxs = (ps[0][2] - ps[0][0]) + 2.f * (ps[1][2] - ps[1][0]) + (ps[2][2] - ps[2][0]);
    float gys = (ps[2][0] + 2.f * ps[2][1] + ps[2][2]) - (ps[0][0] + 2.f * ps[0][1] + ps[0][2]);
    float latf = (float)(-M_PI * 0.5 + (double)y * (M_PI / (double)(Hq - 1)));
    float metric = (float)(1.0 / (cos((double)latf) + 1e-6));
    float u = gxp * metric - gys;
    float v = gyp + gxs * metric;
    flow[(size_t)(l * 2 + 0) * HWq + rem] = tanhf(u);
    flow[(size_t)(l * 2 + 1) * HWq + rem] = tanhf(v);
}

// warp (bilinear, border clamp) + add x_t + mean over R + row sums.
// h state is fp16 (arith in fp32): 4x 16B gather loads/px instead of 8x,
// half the gather bytes/lines. TI = float for l==0 (reads fp32 h0).
// XCD-pinned bid mapping kept from R4 (ideal FETCH).
template <typename TI>
__global__ void k_warp(const TI* __restrict__ hin, h8* __restrict__ hout,
                       const float* __restrict__ flow_l, const float* __restrict__ xl,
                       const float* __restrict__ listT, int l,
                       float* __restrict__ xf, float* __restrict__ rowsum) {
    int bid = blockIdx.x;
    int xcd = bid & 7;
    int local = bid >> 3;
    int c = xcd + 8 * (local / Hq);
    int y = local % Hq;
    int tid = threadIdx.x;
    int wave = tid >> 6, lane = tid & 63;
    float dt = listT[l];
    float gyn = y * (2.0f / (Hq - 1)) - 1.0f;
    const float* flu = flow_l + y * Wq;
    const float* flv = flow_l + HWq + y * Wq;
    const float* xrow = xl + (size_t)c * HWq + y * Wq;
    float* xfrow = xf + (size_t)(c * Hq + y) * Wq;
    float partial = 0.f;
#pragma unroll 2
    for (int x = tid; x < Wq; x += 256) {
        float u = flu[x];
        float v = flv[x];
        float gxn = x * (2.0f / (Wq - 1)) - 1.0f;
        float gx = gxn - u * dt;
        float gy = gyn - v * dt;
        float xp = (gx + 1.0f) * (Wq * 0.5f) - 0.5f;
        float yp = (gy + 1.0f) * (Hq * 0.5f) - 0.5f;
        xp = fminf(fmaxf(xp, 0.0f), (float)(Wq - 1));
        yp = fminf(fmaxf(yp, 0.0f), (float)(Hq - 1));
        float x0f = floorf(xp), y0f = floorf(yp);
        float wx = xp - x0f, wy = yp - y0f;
        int x0 = (int)x0f, y0 = (int)y0f;
        int x1 = min(x0 + 1, Wq - 1), y1 = min(y0 + 1, Hq - 1);
        int i00 = (c * Hq + y0) * Wq + x0, i01 = (c * Hq + y0) * Wq + x1;
        int i10 = (c * Hq + y1) * Wq + x0, i11 = (c * Hq + y1) * Wq + x1;
        float w00 = (1.f - wx) * (1.f - wy), w01 = wx * (1.f - wy);
        float w10 = (1.f - wx) * wy, w11 = wx * wy;
        float r[8];
        if constexpr (sizeof(TI) == 4) {
            const float4* h4 = (const float4*)hin;
            float4 a0 = h4[i00 * 2], b0 = h4[i01 * 2], c0 = h4[i10 * 2], d0 = h4[i11 * 2];
            float4 a1 = h4[i00 * 2 + 1], b1 = h4[i01 * 2 + 1], c1 = h4[i10 * 2 + 1], d1 = h4[i11 * 2 + 1];
            r[0] = w00 * a0.x + w01 * b0.x + w10 * c0.x + w11 * d0.x;
            r[1] = w00 * a0.y + w01 * b0.y + w10 * c0.y + w11 * d0.y;
            r[2] = w00 * a0.z + w01 * b0.z + w10 * c0.z + w11 * d0.z;
            r[3] = w00 * a0.w + w01 * b0.w + w10 * c0.w + w11 * d0.w;
            r[4] = w00 * a1.x + w01 * b1.x + w10 * c1.x + w11 * d1.x;
            r[5] = w00 * a1.y + w01 * b1.y + w10 * c1.y + w11 * d1.y;
            r[6] = w00 * a1.z + w01 * b1.z + w10 * c1.z + w11 * d1.z;
            r[7] = w00 * a1.w + w01 * b1.w + w10 * c1.w + w11 * d1.w;
        } else {
            const h8* hp = (const h8*)hin;
            h8 A = hp[i00], B = hp[i01], C = hp[i10], D = hp[i11];
#pragma unroll
            for (int k = 0; k < 8; k++)
                r[k] = w00 * __half2float(A.v[k]) + w01 * __half2float(B.v[k]) +
                       w10 * __half2float(C.v[k]) + w11 * __half2float(D.v[k]);
        }
        float ssum = r[0] + r[1] + r[2] + r[3] + r[4] + r[5] + r[6] + r[7];
        float xt = xrow[x];
        h8 o;
#pragma unroll
        for (int k = 0; k < 8; k++) o.v[k] = __float2half(r[k] + xt);
        hout[(c * Hq + y) * Wq + x] = o;
        float meanv = ssum * 0.125f + xt;
        xfrow[x] = meanv;
        partial += meanv;
    }
#pragma unroll
    for (int off = 32; off > 0; off >>= 1) partial += __shfl_down(partial, off, 64);
    __shared__ float sred[4];
    if (lane == 0) sred[wave] = partial;
    __syncthreads();
    if (tid == 0) rowsum[c * Hq + y] = sred[0] + sred[1] + sred[2] + sred[3];
}

// SE gate (recomputed per block from rowsums) + apply: out = xf * gate
__global__ void k_apply(const float* __restrict__ xf, const float* __restrict__ rowsum,
                        const float* __restrict__ sw1, const float* __restrict__ sb1,
                        const float* __restrict__ sw2, const float* __restrict__ sb2,
                        float* __restrict__ out_l) {
    int c = blockIdx.x / Hq, y = blockIdx.x % Hq;
    float ym[Cq];
#pragma unroll
    for (int i = 0; i < Cq; i++) ym[i] = rowsum[i * Hq + y] * (1.0f / Wq);
    float z[SEM];
#pragma unroll
    for (int m = 0; m < SEM; m++) {
        float a = sb1[m];
#pragma unroll
        for (int i = 0; i < Cq; i++) a = fmaf(sw1[m * Cq + i], ym[i], a);
        z[m] = a * sigmoidf_(a);
    }
    float a = sb2[c];
#pragma unroll
    for (int m = 0; m < SEM; m++) a = fmaf(sw2[c * SEM + m], z[m], a);
    float gv = sigmoidf_(a);
    const float4* s4 = (const float4*)(xf + (size_t)(c * Hq + y) * Wq);
    float4* d4 = (float4*)(out_l + (size_t)(c * Hq + y) * Wq);
    for (int i = threadIdx.x; i < Wq / 4; i += blockDim.x) {
        float4 v = s4[i];
        v.x *= gv; v.y *= gv; v.z *= gv; v.w *= gv;
        d4[i] = v;
    }
}

extern "C" void kernel_launch(void* const* d_in, const int* in_sizes, int n_in,
                              void* d_out, int out_size, void* d_ws, size_t ws_size,
                              hipStream_t stream) {
    const float* x = (const float*)d_in[0];
    const float* h0 = (const float*)d_in[1];
    const float* listT = (const float*)d_in[2];
    const float* hw1 = (const float*)d_in[3];
    const float* hb1 = (const float*)d_in[4];
    const float* hw2 = (const float*)d_in[5];
    const float* hb2 = (const float*)d_in[6];
    const float* sw1 = (const float*)d_in[7];
    const float* sb1 = (const float*)d_in[8];
    const float* sw2 = (const float*)d_in[9];
    const float* sb2 = (const float*)d_in[10];
    float* out = (float*)d_out;
    char* ws = (char*)d_ws;

    size_t off = 0;
    float* flow = (float*)(ws + off); off += sizeof(float) * (size_t)Lq * 2 * HWq;
    float* f    = (float*)(ws + off); off += sizeof(float) * (size_t)Lq * 2 * HWq;
    float* f1   = (float*)(ws + off); off += sizeof(float) * (size_t)Lq * MIDq * HWq;
    h8* hA      = (h8*)(ws + off);    off += sizeof(h8) * (size_t)Cq * HWq;
    h8* hB      = (h8*)(ws + off);    off += sizeof(h8) * (size_t)Cq * HWq;
    float* xf   = (float*)(ws + off); off += sizeof(float) * (size_t)Cq * HWq;
    float* rows = (float*)(ws + off); off += sizeof(float) * (size_t)Cq * Hq;

    k_conv1<<<Lq * Hq, 128, 0, stream>>>(x, hw1, hb1, f1);
    k_conv2<<<Lq * Hq, 128, 0, stream>>>(f1, hw2, hb2, f);
    k_flow<<<(Lq * HWq + 255) / 256, 256, 0, stream>>>(f, flow);

    h8* bufs[2] = {hA, hB};
    for (int l = 0; l < Lq; l++) {
        h8* hout = bufs[l & 1];
        if (l == 0) {
            k_warp<float><<<Cq * Hq, 256, 0, stream>>>(h0, hout, flow,
                                                       x, listT, 0, xf, rows);
        } else {
            k_warp<__half><<<Cq * Hq, 256, 0, stream>>>((const __half*)bufs[(l - 1) & 1], hout,
                                                        flow + (size_t)l * 2 * HWq,
                                                        x + (size_t)l * Cq * HWq, listT, l, xf, rows);
        }
        k_apply<<<Cq * Hq, 128, 0, stream>>>(xf, rows, sw1, sb1, sw2, sb2,
                                             out + (size_t)l * Cq * HWq);
    }
}